// Round 11
// baseline (71.873 us; speedup 1.0000x reference)
//
#include <hip/hip_runtime.h>
#include <math.h>

#define H_ 768
#define W_ 768
#define TILE 32
#define EXT 36
#define BROW 44   // sBp row stride: 2 left-pad + 40 data + 2 slack (16B-aligned rows)
#define EPS_ 1e-6f

typedef float vfloat4 __attribute__((ext_vector_type(4)));

// normalized gabor45 kernel (precomputed offline, _norm applied); g135 = column mirror
__constant__ float GW[25] = {
   -0.00209120f, -0.01519473f, -0.06332027f, -0.00228457f,  0.03651120f,
   -0.01519473f, -0.08630971f,  0.00380376f,  0.11945652f, -0.00228457f,
   -0.06332027f,  0.00380376f,  0.17285313f,  0.00380376f, -0.06332027f,
   -0.00228457f,  0.11945652f,  0.00380376f, -0.08630971f, -0.01519473f,
    0.03651120f, -0.00228457f, -0.06332027f, -0.01519473f, -0.00209120f
};

__device__ __forceinline__ int refl(int i, int n) {
    i = (i < 0) ? -i : i;
    return (i >= n) ? (2 * n - 2 - i) : i;
}

// LDS layout (31872 B):
//  sGG  [0,10368)      float2[36*36] (gx,gy)
//  sCD  [10368,20736)  float2[36*36] (rg,bg)
//  sBp  [20736,27776)  float[40*44]  bayer (+2 col shift)
//  sGPD [27776,31872)  float[32*32]

#define STORE4(ch, a) do { \
    vfloat4 _v = { (a)[0], (a)[1], (a)[2], (a)[3] }; \
    *(vfloat4*)(p + (size_t)(ch) * HW) = _v; \
} while (0)

__global__ __launch_bounds__(256, 4)
void bayer_feat_kernel(const float* __restrict__ in, float* __restrict__ out) {
    __shared__ __align__(16) char smem[31872];
    float2* const sGG  = (float2*)(smem);
    float2* const sCD  = (float2*)(smem + 10368);
    float*  const sBp  = (float*) (smem + 20736);
    float*  const sGPD = (float*) (smem + 27776);

    const int tid = threadIdx.x;
    const int x0 = blockIdx.x * TILE;
    const int y0 = blockIdx.y * TILE;
    const int bz = blockIdx.z;
    const float* __restrict__ inb = in + (size_t)bz * H_ * W_;
    const bool border = (x0 == 0) | (x0 + TILE == W_) | (y0 == 0) | (y0 + TILE == H_);

    // ---- phase 1: bayer tile + halo 4 ----
    if (border) {
        for (int i = tid; i < 1600; i += 256) {
            int iy = i / 40, ix = i - iy * 40;
            sBp[iy * BROW + ix + 2] = inb[refl(y0 - 4 + iy, H_) * W_ + refl(x0 - 4 + ix, W_)];
        }
    } else {
        for (int i = tid; i < 1600; i += 256) {
            int iy = i / 40, ix = i - iy * 40;
            sBp[iy * BROW + ix + 2] = inb[(y0 - 4 + iy) * W_ + (x0 - 4 + ix)];
        }
    }
    __syncthreads();

    const float w5c[5] = {1.f, 2.f, 3.f, 2.f, 1.f};

    // ---- phase 2: ext 36x36 -> gx/gy, rg/bg, gpd (reflect-at-fill) ----
    for (int i = tid; i < EXT * EXT; i += 256) {
        int ey = i / EXT, ex = i - ey * EXT;
        int ry, rx, p_r, p_c;
        if (border) {
            int py = refl(y0 - 2 + ey, H_), pxc = refl(x0 - 2 + ex, W_);
            ry = py - (y0 - 4); rx = pxc - (x0 - 4);
            p_r = py & 1; p_c = pxc & 1;
        } else {
            ry = ey + 2; rx = ex + 2;
            p_r = ey & 1; p_c = ex & 1;
        }
        const float* bC = sBp + ry * BROW + rx + 2;

        float bmm = bC[-BROW-1], bm0 = bC[-BROW], bmp = bC[-BROW+1];
        float b0m = bC[-1],                        b0p = bC[1];
        float bpm = bC[BROW-1],  bp0 = bC[BROW],  bpp = bC[BROW+1];
        sGG[i] = make_float2(((bmp - bmm) + 2.f*(b0p - b0m) + (bpp - bpm)) * 0.125f,
                             ((bpm - bmm) + 2.f*(bp0 - bm0) + (bpp - bmp)) * 0.125f);

        float A0 = 0.f, A1 = 0.f, B0 = 0.f, B1 = 0.f;
        #pragma unroll
        for (int dy = 0; dy < 5; ++dy) {
            const float* row = bC + (dy - 2) * BROW;
            float cs = row[-2] + 3.f*row[0] + row[2];
            float cd = 2.f*(row[-1] + row[1]);
            float wy = w5c[dy];
            if (dy & 1) { B0 += wy * cs; B1 += wy * cd; }
            else        { A0 += wy * cs; A1 += wy * cd; }
        }
        float rA0 = p_r ? B0 : A0;
        float rA1 = p_r ? B1 : A1;
        float rB0 = p_r ? A0 : B0;
        float rB1 = p_r ? A1 : B1;
        float n_gb = p_c ? rA1 : rA0;
        float n_b  = p_c ? rA0 : rA1;
        float n_r  = p_c ? rB1 : rB0;
        float n_gr = p_c ? rB0 : rB1;

        float inv_r  = p_r ? (p_c ? 0.05f   : 0.04f)   : (p_c ? 0.0625f : 0.05f);
        float inv_b  = p_r ? (p_c ? 0.05f   : 0.0625f) : (p_c ? 0.04f   : 0.05f);
        float inv_gr = p_r ? (p_c ? 0.04f   : 0.05f)   : (p_c ? 0.05f   : 0.0625f);
        float inv_gb = p_r ? (p_c ? 0.0625f : 0.05f)   : (p_c ? 0.05f   : 0.04f);
        float inv_g  = (p_r == p_c) ? 0.024390243902439025f : 0.025f;

        float fr  = n_r  * inv_r;
        float fb  = n_b  * inv_b;
        float fgr = n_gr * inv_gr;
        float fgb = n_gb * inv_gb;
        float fg  = (n_gr + n_gb) * inv_g;

        sCD[i] = make_float2(fr - fg, fb - fg);
        if (ey >= 2 && ey < 34 && ex >= 2 && ex < 34)
            sGPD[(ey - 2) * 32 + (ex - 2)] = fgr - fgb;
    }
    __syncthreads();

    const size_t HW = (size_t)H_ * W_;
    float* __restrict__ outb = out + (size_t)bz * 30 * HW;

    // ---- phase 3: pixel-quad, three sequential low-pressure parts ----
    {
        const int ty = tid >> 3;
        const int tx4 = (tid & 7) << 2;
        const int gy = y0 + ty;
        float* p = outb + (size_t)gy * W_ + (x0 + tx4);

        float gdm4[4], gda4[4], hf4[4];   // persist A->B

        // ======== part A: bayer-tap channels (t live only here) ========
        {
            float t[5][8];
            {
                const int rb = (ty + 2) * BROW + tx4 + 4;
                #pragma unroll
                for (int r = 0; r < 5; ++r) {
                    float4 a = *(const float4*)&sBp[rb + r * BROW];
                    float4 b = *(const float4*)&sBp[rb + r * BROW + 4];
                    t[r][0]=a.x; t[r][1]=a.y; t[r][2]=a.z; t[r][3]=a.w;
                    t[r][4]=b.x; t[r][5]=b.y; t[r][6]=b.z; t[r][7]=b.w;
                }
            }

            #pragma unroll
            for (int q = 0; q < 4; ++q) {
                float bmm=t[1][q+1], bm0=t[1][q+2], bmp=t[1][q+3];
                float b0m=t[2][q+1],                 b0p=t[2][q+3];
                float bpm=t[3][q+1], bp0=t[3][q+2], bpp=t[3][q+3];
                gdm4[q] = (-2.f*bmm - bm0 - b0m + b0p + bp0 + 2.f*bpp) * 0.125f;
                gda4[q] = (bm0 + 2.f*bmp - b0m + b0p - 2.f*bpm - bp0) * 0.125f;
            }
            STORE4(2, gdm4);
            STORE4(3, gda4);

            {
                float lap4[4], lmx4[4], lmn4[4];
                #pragma unroll
                for (int q = 0; q < 4; ++q) {
                    float hxx = t[2][q+1] - 2.f*t[2][q+2] + t[2][q+3];
                    float hyy = t[1][q+2] - 2.f*t[2][q+2] + t[3][q+2];
                    float hxy = (t[1][q+1] - t[1][q+3] - t[3][q+1] + t[3][q+3]) * 0.25f;
                    lap4[q] = hxx + hyy;
                    float hm = 0.5f * (hxx + hyy);
                    float hsd = 0.5f * (hxx - hyy);
                    float hs = sqrtf(hsd*hsd + hxy*hxy + EPS_);
                    lmx4[q] = hm + hs; lmn4[q] = hm - hs;
                }
                STORE4(5, lap4); STORE4(6, lmx4); STORE4(7, lmn4);
            }
            {
                float gir4[4];
                #pragma unroll
                for (int q = 0; q < 4; ++q) {
                    float sumx = t[1][q+2] + t[2][q+1] + t[2][q+3] + t[3][q+2];
                    float sumc = t[1][q+1] + t[1][q+3] + t[3][q+1] + t[3][q+3];
                    hf4[q] = (sumc - 2.f*sumx + 4.f*t[2][q+2]) * 0.0625f;
                    float gcross = 0.25f * sumx;
                    gir4[q] = ((ty & 1) == (q & 1)) ? (t[2][q+2] - gcross) : 0.f;
                }
                STORE4(17, gir4);
            }
            {
                float pr = (float)(ty & 1);
                float rm4[4] = {pr, 0.f, pr, 0.f};
                float bm4[4] = {0.f, 1.f - pr, 0.f, 1.f - pr};
                float gm4[4] = {1.f - pr, pr, 1.f - pr, pr};
                STORE4(11, rm4); STORE4(12, gm4); STORE4(13, bm4);
            }
            {
                float dgc4[4];
                #pragma unroll
                for (int q = 0; q < 4; ++q) {
                    float gh = 0.5f*(t[2][q+1] + t[2][q+2] + t[2][q+3]) - 0.25f*(t[2][q] + t[2][q+4]);
                    float gv = 0.5f*(t[1][q+2] + t[2][q+2] + t[3][q+2]) - 0.25f*(t[0][q+2] + t[4][q+2]);
                    dgc4[q] = fabsf(gh - gv);
                }
                STORE4(18, dgc4);
            }

            // gabors (hardcoded weights; g135 = column mirror)
            {
                float g45[4] = {0.f,0.f,0.f,0.f}, g135[4] = {0.f,0.f,0.f,0.f};
                #pragma unroll
                for (int dy = 0; dy < 5; ++dy) {
                    #pragma unroll
                    for (int dx = 0; dx < 5; ++dx) {
                        const float w = GW[dy * 5 + dx];
                        #pragma unroll
                        for (int q = 0; q < 4; ++q) {
                            g45[q]  = fmaf(w, t[dy][q + dx],     g45[q]);
                            g135[q] = fmaf(w, t[dy][q + 4 - dx], g135[q]);
                        }
                    }
                }
                float oe4[4];
                #pragma unroll
                for (int q = 0; q < 4; ++q) oe4[q] = sqrtf(g45[q]*g45[q] + g135[q]*g135[q] + EPS_);
                STORE4(10, oe4);
            }

            // separable 5x5 bank via register column-profiles
            {
                float Vo[8], Va[8], Vs_[8], Vc_[8], Vd_[8];
                #pragma unroll
                for (int c = 0; c < 8; ++c) {
                    float v0=t[0][c], v1=t[1][c], v2=t[2][c], v3=t[3][c], v4=t[4][c];
                    Vo[c] = v0 + v1 + v2 + v3 + v4;
                    Va[c] = v0 - v1 + v2 - v3 + v4;
                    Vs_[c] = 0.95105651629515f*(v1 - v4) + 0.58778525229247f*(v2 - v3);
                    Vc_[c] = v0 + 0.30901699437495f*(v1 + v4) - 0.80901699437495f*(v2 + v3);
                    Vd_[c] = 0.80901699437495f*(v0 + v4) - 0.30901699437495f*(v1 + v3) - v2;
                }
                float cb4[4], sh4[4], sv4[4], sx4[4], sy4[4], ph4[4], hb4[4];
                #pragma unroll
                for (int q = 0; q < 4; ++q) {
                    float box = Vo[q] + Vo[q+1] + Vo[q+2] + Vo[q+3] + Vo[q+4];
                    float shr = Vo[q] - Vo[q+1] + Vo[q+2] - Vo[q+3] + Vo[q+4];
                    float sxr = 0.95105651629515f*(Vo[q+1] - Vo[q+4]) + 0.58778525229247f*(Vo[q+2] - Vo[q+3]);
                    float pxr = Vo[q] + 0.30901699437495f*(Vo[q+1] + Vo[q+4]) - 0.80901699437495f*(Vo[q+2] + Vo[q+3]);
                    float cbr = Va[q] - Va[q+1] + Va[q+2] - Va[q+3] + Va[q+4];
                    float svr = Va[q] + Va[q+1] + Va[q+2] + Va[q+3] + Va[q+4];
                    float syr = Vs_[q] + Vs_[q+1] + Vs_[q+2] + Vs_[q+3] + Vs_[q+4];
                    float pyr = Vc_[q] + Vc_[q+1] + Vc_[q+2] + Vc_[q+3] + Vc_[q+4];
                    float dctr = 0.80901699437495f*(Vd_[q] + Vd_[q+4]) - 0.30901699437495f*(Vd_[q+1] + Vd_[q+3]) - Vd_[q+2];

                    cb4[q] = fabsf((cbr - 0.04f * box) * 0.04006410256410f);
                    sh4[q] = (shr - 0.2f * box) * 0.04166666666667f;
                    sv4[q] = (svr - 0.2f * box) * 0.04166666666667f;
                    sx4[q] = sxr * 0.06498394f;
                    sy4[q] = syr * 0.06498394f;
                    float px_n = pxr * 0.06180339887f;
                    float py_n = pyr * 0.06180339887f;
                    ph4[q] = sqrtf(px_n*px_n + py_n*py_n + EPS_);
                    float dct_n = dctr * 0.09549150281f;
                    hb4[q] = sqrtf(dct_n*dct_n + hf4[q]*hf4[q] + EPS_);
                }
                STORE4(21, cb4); STORE4(22, sh4); STORE4(23, sv4);
                STORE4(24, sh4); STORE4(25, sv4); STORE4(26, ph4);
                STORE4(27, sx4); STORE4(28, sy4); STORE4(29, hb4);
            }
        }   // t, V dead

        // ======== part B: J pass (reads sGG only; 24 accumulators) ========
        {
            float cJxx[8] = {0,0,0,0,0,0,0,0}, cJyy[8] = {0,0,0,0,0,0,0,0}, cJxy[8] = {0,0,0,0,0,0,0,0};
            float gx4[4], gy4[4];
            #pragma unroll
            for (int dy = 0; dy < 5; ++dy) {
                const float wy = w5c[dy];
                float gxr[8], gyr[8];
                {
                    const float4* g4 = (const float4*)(sGG + (ty + dy) * 36 + tx4);
                    float4 a = g4[0], b = g4[1], c = g4[2], d = g4[3];
                    gxr[0]=a.x; gyr[0]=a.y; gxr[1]=a.z; gyr[1]=a.w;
                    gxr[2]=b.x; gyr[2]=b.y; gxr[3]=b.z; gyr[3]=b.w;
                    gxr[4]=c.x; gyr[4]=c.y; gxr[5]=c.z; gyr[5]=c.w;
                    gxr[6]=d.x; gyr[6]=d.y; gxr[7]=d.z; gyr[7]=d.w;
                }
                #pragma unroll
                for (int c = 0; c < 8; ++c) {
                    cJxx[c] = fmaf(wy, gxr[c]*gxr[c], cJxx[c]);
                    cJyy[c] = fmaf(wy, gyr[c]*gyr[c], cJyy[c]);
                    cJxy[c] = fmaf(wy, gxr[c]*gyr[c], cJxy[c]);
                }
                if (dy == 2) {
                    #pragma unroll
                    for (int q = 0; q < 4; ++q) { gx4[q] = gxr[q+2]; gy4[q] = gyr[q+2]; }
                }
            }
            float an4[4];
            const float inv81 = 1.f / 81.f;
            #pragma unroll
            for (int q = 0; q < 4; ++q) {
                float xx = (cJxx[q] + 2.f*cJxx[q+1] + 3.f*cJxx[q+2] + 2.f*cJxx[q+3] + cJxx[q+4]) * inv81;
                float yy = (cJyy[q] + 2.f*cJyy[q+1] + 3.f*cJyy[q+2] + 2.f*cJyy[q+3] + cJyy[q+4]) * inv81;
                float xy = (cJxy[q] + 2.f*cJxy[q+1] + 3.f*cJxy[q+2] + 2.f*cJxy[q+3] + cJxy[q+4]) * inv81;
                float jd = 0.5f * (xx - yy);
                an4[q] = 2.f * sqrtf(jd*jd + xy*xy + EPS_) / (xx + yy + EPS_);
            }
            STORE4(8, an4);
            STORE4(0, gx4);
            STORE4(1, gy4);
            {
                float gm4[4], dv4[4];
                #pragma unroll
                for (int q = 0; q < 4; ++q) {
                    gm4[q] = sqrtf(gx4[q]*gx4[q] + gy4[q]*gy4[q] + EPS_);
                    float md  = 0.25f * (gx4[q] + gy4[q] + gdm4[q] + gda4[q]);
                    float m2d = 0.25f * (gx4[q]*gx4[q] + gy4[q]*gy4[q] + gdm4[q]*gdm4[q] + gda4[q]*gda4[q]);
                    dv4[q] = m2d - md * md;
                }
                STORE4(4, gm4);
                STORE4(9, dv4);
            }
        }   // cJ dead

        // ======== part C: moments pass (reads sCD only; 32 accumulators) ========
        {
            float c1r[8] = {0,0,0,0,0,0,0,0}, c2r[8] = {0,0,0,0,0,0,0,0};
            float c1b[8] = {0,0,0,0,0,0,0,0}, c2b[8] = {0,0,0,0,0,0,0,0};
            float rg4[4], bg4[4];
            #pragma unroll
            for (int dy = 0; dy < 5; ++dy) {
                float cr[8], cb[8];
                {
                    const float4* c4 = (const float4*)(sCD + (ty + dy) * 36 + tx4);
                    float4 a = c4[0], b = c4[1], c_ = c4[2], d = c4[3];
                    cr[0]=a.x; cb[0]=a.y; cr[1]=a.z; cb[1]=a.w;
                    cr[2]=b.x; cb[2]=b.y; cr[3]=b.z; cb[3]=b.w;
                    cr[4]=c_.x; cb[4]=c_.y; cr[5]=c_.z; cb[5]=c_.w;
                    cr[6]=d.x; cb[6]=d.y; cr[7]=d.z; cb[7]=d.w;
                }
                #pragma unroll
                for (int c = 0; c < 8; ++c) {
                    c1r[c] += cr[c]; c2r[c] = fmaf(cr[c], cr[c], c2r[c]);
                    c1b[c] += cb[c]; c2b[c] = fmaf(cb[c], cb[c], c2b[c]);
                }
                if (dy == 2) {
                    #pragma unroll
                    for (int q = 0; q < 4; ++q) { rg4[q] = cr[q+2]; bg4[q] = cb[q+2]; }
                }
            }
            float cv4[4], ch4[4];
            #pragma unroll
            for (int q = 0; q < 4; ++q) {
                float a1r = (c1r[q] + c1r[q+1] + c1r[q+2] + c1r[q+3] + c1r[q+4]) * 0.04f;
                float a2r = (c2r[q] + c2r[q+1] + c2r[q+2] + c2r[q+3] + c2r[q+4]) * 0.04f;
                float a1b = (c1b[q] + c1b[q+1] + c1b[q+2] + c1b[q+3] + c1b[q+4]) * 0.04f;
                float a2b = (c2b[q] + c2b[q+1] + c2b[q+2] + c2b[q+3] + c2b[q+4]) * 0.04f;
                cv4[q] = fmaxf(a2r - a1r*a1r, 0.f) + fmaxf(a2b - a1b*a1b, 0.f);
                ch4[q] = sqrtf(rg4[q]*rg4[q] + bg4[q]*bg4[q] + EPS_);
            }
            STORE4(20, cv4);
            STORE4(15, rg4);
            STORE4(16, bg4);
            STORE4(19, ch4);
            {
                float4 gp = *(const float4*)(sGPD + ty * 32 + tx4);
                float gp4[4] = {gp.x, gp.y, gp.z, gp.w};
                STORE4(14, gp4);
            }
        }
    }
}

extern "C" void kernel_launch(void* const* d_in, const int* in_sizes, int n_in,
                              void* d_out, int out_size, void* d_ws, size_t ws_size,
                              hipStream_t stream) {
    const float* bayer = (const float*)d_in[0];
    float* out = (float*)d_out;
    (void)in_sizes; (void)n_in; (void)out_size; (void)d_ws; (void)ws_size;

    dim3 grid(W_ / TILE, H_ / TILE, 4);
    bayer_feat_kernel<<<grid, dim3(256), 0, stream>>>(bayer, out);
}

// Round 12
// 63.921 us; speedup vs baseline: 1.1244x; 1.1244x over previous
//
#include <hip/hip_runtime.h>
#include <math.h>

#define H_ 768
#define W_ 768
#define TILE 32
#define EXT 36
#define BROW 44   // sBp row stride: 2 left-pad + 40 data + 2 slack (16B-aligned rows)
#define EPS_ 1e-6f

typedef float vfloat4 __attribute__((ext_vector_type(4)));

// normalized gabor45 kernel (precomputed offline, _norm applied); g135 = column mirror
__constant__ float GW[25] = {
   -0.00209120f, -0.01519473f, -0.06332027f, -0.00228457f,  0.03651120f,
   -0.01519473f, -0.08630971f,  0.00380376f,  0.11945652f, -0.00228457f,
   -0.06332027f,  0.00380376f,  0.17285313f,  0.00380376f, -0.06332027f,
   -0.00228457f,  0.11945652f,  0.00380376f, -0.08630971f, -0.01519473f,
    0.03651120f, -0.00228457f, -0.06332027f, -0.01519473f, -0.00209120f
};

__device__ __forceinline__ int refl(int i, int n) {
    i = (i < 0) ? -i : i;
    return (i >= n) ? (2 * n - 2 - i) : i;
}

// LDS layout (31872 B, no overlays):
//  sGG  [0,10368)      float2[36*36] (gx,gy)
//  sCD  [10368,20736)  float2[36*36] (rg,bg)
//  sBp  [20736,27776)  float[40*44]  bayer (+2 col shift)
//  sGPD [27776,31872)  float[32*32]

#define STORE4(ch, a) do { \
    vfloat4 _v = { (a)[0], (a)[1], (a)[2], (a)[3] }; \
    *(vfloat4*)(p + (size_t)(ch) * HW) = _v; \
} while (0)

__global__ __launch_bounds__(256, 3)
void bayer_feat_kernel(const float* __restrict__ in, float* __restrict__ out) {
    __shared__ __align__(16) char smem[31872];
    float2* const sGG  = (float2*)(smem);
    float2* const sCD  = (float2*)(smem + 10368);
    float*  const sBp  = (float*) (smem + 20736);
    float*  const sGPD = (float*) (smem + 27776);

    const int tid = threadIdx.x;
    const int x0 = blockIdx.x * TILE;
    const int y0 = blockIdx.y * TILE;
    const int bz = blockIdx.z;
    const float* __restrict__ inb = in + (size_t)bz * H_ * W_;
    const bool border = (x0 == 0) | (x0 + TILE == W_) | (y0 == 0) | (y0 + TILE == H_);

    // ---- phase 1: bayer tile + halo 4 ----
    if (border) {
        for (int i = tid; i < 1600; i += 256) {
            int iy = i / 40, ix = i - iy * 40;
            sBp[iy * BROW + ix + 2] = inb[refl(y0 - 4 + iy, H_) * W_ + refl(x0 - 4 + ix, W_)];
        }
    } else {
        for (int i = tid; i < 1600; i += 256) {
            int iy = i / 40, ix = i - iy * 40;
            sBp[iy * BROW + ix + 2] = inb[(y0 - 4 + iy) * W_ + (x0 - 4 + ix)];
        }
    }
    __syncthreads();

    const float w5c[5] = {1.f, 2.f, 3.f, 2.f, 1.f};

    // ---- phase 2: ext 36x36 -> gx/gy, rg/bg, gpd (reflect-at-fill) ----
    for (int i = tid; i < EXT * EXT; i += 256) {
        int ey = i / EXT, ex = i - ey * EXT;
        int ry, rx, p_r, p_c;
        if (border) {
            int py = refl(y0 - 2 + ey, H_), pxc = refl(x0 - 2 + ex, W_);
            ry = py - (y0 - 4); rx = pxc - (x0 - 4);
            p_r = py & 1; p_c = pxc & 1;
        } else {
            ry = ey + 2; rx = ex + 2;
            p_r = ey & 1; p_c = ex & 1;
        }
        const float* bC = sBp + ry * BROW + rx + 2;

        float bmm = bC[-BROW-1], bm0 = bC[-BROW], bmp = bC[-BROW+1];
        float b0m = bC[-1],                        b0p = bC[1];
        float bpm = bC[BROW-1],  bp0 = bC[BROW],  bpp = bC[BROW+1];
        sGG[i] = make_float2(((bmp - bmm) + 2.f*(b0p - b0m) + (bpp - bpm)) * 0.125f,
                             ((bpm - bmm) + 2.f*(bp0 - bm0) + (bpp - bmp)) * 0.125f);

        float A0 = 0.f, A1 = 0.f, B0 = 0.f, B1 = 0.f;
        #pragma unroll
        for (int dy = 0; dy < 5; ++dy) {
            const float* row = bC + (dy - 2) * BROW;
            float cs = row[-2] + 3.f*row[0] + row[2];
            float cd = 2.f*(row[-1] + row[1]);
            float wy = w5c[dy];
            if (dy & 1) { B0 += wy * cs; B1 += wy * cd; }
            else        { A0 += wy * cs; A1 += wy * cd; }
        }
        float rA0 = p_r ? B0 : A0;
        float rA1 = p_r ? B1 : A1;
        float rB0 = p_r ? A0 : B0;
        float rB1 = p_r ? A1 : B1;
        float n_gb = p_c ? rA1 : rA0;
        float n_b  = p_c ? rA0 : rA1;
        float n_r  = p_c ? rB1 : rB0;
        float n_gr = p_c ? rB0 : rB1;

        float inv_r  = p_r ? (p_c ? 0.05f   : 0.04f)   : (p_c ? 0.0625f : 0.05f);
        float inv_b  = p_r ? (p_c ? 0.05f   : 0.0625f) : (p_c ? 0.04f   : 0.05f);
        float inv_gr = p_r ? (p_c ? 0.04f   : 0.05f)   : (p_c ? 0.05f   : 0.0625f);
        float inv_gb = p_r ? (p_c ? 0.0625f : 0.05f)   : (p_c ? 0.05f   : 0.04f);
        float inv_g  = (p_r == p_c) ? 0.024390243902439025f : 0.025f;

        float fr  = n_r  * inv_r;
        float fb  = n_b  * inv_b;
        float fgr = n_gr * inv_gr;
        float fgb = n_gb * inv_gb;
        float fg  = (n_gr + n_gb) * inv_g;

        sCD[i] = make_float2(fr - fg, fb - fg);
        if (ey >= 2 && ey < 34 && ex >= 2 && ex < 34)
            sGPD[(ey - 2) * 32 + (ex - 2)] = fgr - fgb;
    }
    __syncthreads();

    const size_t HW = (size_t)H_ * W_;
    float* __restrict__ outb = out + (size_t)bz * 30 * HW;

    // ---- phase 3: pixel-quad, all 30 channels, zero post-store barriers ----
    {
        const int ty = tid >> 3;
        const int tx4 = (tid & 7) << 2;
        const int gy = y0 + ty;
        float* p = outb + (size_t)gy * W_ + (x0 + tx4);

        // part 0: separable J (smooth5 of gx/gy products) + chroma moments (box5)
        // via register COLUMN accumulators (wy-weighted vertical sums), then one
        // horizontal 5-tap combine.
        float cJxx[8] = {0,0,0,0,0,0,0,0}, cJyy[8] = {0,0,0,0,0,0,0,0}, cJxy[8] = {0,0,0,0,0,0,0,0};
        float c1r[8] = {0,0,0,0,0,0,0,0}, c2r[8] = {0,0,0,0,0,0,0,0};
        float c1b[8] = {0,0,0,0,0,0,0,0}, c2b[8] = {0,0,0,0,0,0,0,0};
        float gx4[4], gy4[4], rg4[4], bg4[4];

        #pragma unroll
        for (int dy = 0; dy < 5; ++dy) {
            const float wy = w5c[dy];
            float gxr[8], gyr[8];
            {
                const float4* g4 = (const float4*)(sGG + (ty + dy) * 36 + tx4);
                float4 a = g4[0], b = g4[1], c = g4[2], d = g4[3];
                gxr[0]=a.x; gyr[0]=a.y; gxr[1]=a.z; gyr[1]=a.w;
                gxr[2]=b.x; gyr[2]=b.y; gxr[3]=b.z; gyr[3]=b.w;
                gxr[4]=c.x; gyr[4]=c.y; gxr[5]=c.z; gyr[5]=c.w;
                gxr[6]=d.x; gyr[6]=d.y; gxr[7]=d.z; gyr[7]=d.w;
            }
            #pragma unroll
            for (int c = 0; c < 8; ++c) {
                cJxx[c] = fmaf(wy, gxr[c]*gxr[c], cJxx[c]);
                cJyy[c] = fmaf(wy, gyr[c]*gyr[c], cJyy[c]);
                cJxy[c] = fmaf(wy, gxr[c]*gyr[c], cJxy[c]);
            }

            float cr[8], cb[8];
            {
                const float4* c4 = (const float4*)(sCD + (ty + dy) * 36 + tx4);
                float4 a = c4[0], b = c4[1], c_ = c4[2], d = c4[3];
                cr[0]=a.x; cb[0]=a.y; cr[1]=a.z; cb[1]=a.w;
                cr[2]=b.x; cb[2]=b.y; cr[3]=b.z; cb[3]=b.w;
                cr[4]=c_.x; cb[4]=c_.y; cr[5]=c_.z; cb[5]=c_.w;
                cr[6]=d.x; cb[6]=d.y; cr[7]=d.z; cb[7]=d.w;
            }
            #pragma unroll
            for (int c = 0; c < 8; ++c) {
                c1r[c] += cr[c]; c2r[c] = fmaf(cr[c], cr[c], c2r[c]);
                c1b[c] += cb[c]; c2b[c] = fmaf(cb[c], cb[c], c2b[c]);
            }

            if (dy == 2) {
                #pragma unroll
                for (int q = 0; q < 4; ++q) {
                    gx4[q] = gxr[q+2]; gy4[q] = gyr[q+2];
                    rg4[q] = cr[q+2];  bg4[q] = cb[q+2];
                }
            }
        }

        float an4[4], cv4[4];
        const float inv81 = 1.f / 81.f;
        #pragma unroll
        for (int q = 0; q < 4; ++q) {
            float xx = (cJxx[q] + 2.f*cJxx[q+1] + 3.f*cJxx[q+2] + 2.f*cJxx[q+3] + cJxx[q+4]) * inv81;
            float yy = (cJyy[q] + 2.f*cJyy[q+1] + 3.f*cJyy[q+2] + 2.f*cJyy[q+3] + cJyy[q+4]) * inv81;
            float xy = (cJxy[q] + 2.f*cJxy[q+1] + 3.f*cJxy[q+2] + 2.f*cJxy[q+3] + cJxy[q+4]) * inv81;
            float jd = 0.5f * (xx - yy);
            an4[q] = 2.f * sqrtf(jd*jd + xy*xy + EPS_) / (xx + yy + EPS_);
            float a1r = (c1r[q] + c1r[q+1] + c1r[q+2] + c1r[q+3] + c1r[q+4]) * 0.04f;
            float a2r = (c2r[q] + c2r[q+1] + c2r[q+2] + c2r[q+3] + c2r[q+4]) * 0.04f;
            float a1b = (c1b[q] + c1b[q+1] + c1b[q+2] + c1b[q+3] + c1b[q+4]) * 0.04f;
            float a2b = (c2b[q] + c2b[q+1] + c2b[q+2] + c2b[q+3] + c2b[q+4]) * 0.04f;
            cv4[q] = fmaxf(a2r - a1r*a1r, 0.f) + fmaxf(a2b - a1b*a1b, 0.f);
        }
        STORE4(8, an4);
        STORE4(20, cv4);
        STORE4(0, gx4);
        STORE4(1, gy4);
        STORE4(15, rg4);
        STORE4(16, bg4);
        {
            float gm4[4], ch4[4];
            #pragma unroll
            for (int q = 0; q < 4; ++q) {
                gm4[q] = sqrtf(gx4[q]*gx4[q] + gy4[q]*gy4[q] + EPS_);
                ch4[q] = sqrtf(rg4[q]*rg4[q] + bg4[q]*bg4[q] + EPS_);
            }
            STORE4(4, gm4);
            STORE4(19, ch4);
        }

        // part 1: bayer-tap channels
        float t[5][8];
        {
            const int rb = (ty + 2) * BROW + tx4 + 4;
            #pragma unroll
            for (int r = 0; r < 5; ++r) {
                float4 a = *(const float4*)&sBp[rb + r * BROW];
                float4 b = *(const float4*)&sBp[rb + r * BROW + 4];
                t[r][0]=a.x; t[r][1]=a.y; t[r][2]=a.z; t[r][3]=a.w;
                t[r][4]=b.x; t[r][5]=b.y; t[r][6]=b.z; t[r][7]=b.w;
            }
        }

        float gdm4[4], gda4[4];
        #pragma unroll
        for (int q = 0; q < 4; ++q) {
            float bmm=t[1][q+1], bm0=t[1][q+2], bmp=t[1][q+3];
            float b0m=t[2][q+1],                 b0p=t[2][q+3];
            float bpm=t[3][q+1], bp0=t[3][q+2], bpp=t[3][q+3];
            gdm4[q] = (-2.f*bmm - bm0 - b0m + b0p + bp0 + 2.f*bpp) * 0.125f;
            gda4[q] = (bm0 + 2.f*bmp - b0m + b0p - 2.f*bpm - bp0) * 0.125f;
        }
        STORE4(2, gdm4);
        STORE4(3, gda4);

        {
            float lap4[4], lmx4[4], lmn4[4];
            #pragma unroll
            for (int q = 0; q < 4; ++q) {
                float hxx = t[2][q+1] - 2.f*t[2][q+2] + t[2][q+3];
                float hyy = t[1][q+2] - 2.f*t[2][q+2] + t[3][q+2];
                float hxy = (t[1][q+1] - t[1][q+3] - t[3][q+1] + t[3][q+3]) * 0.25f;
                lap4[q] = hxx + hyy;
                float hm = 0.5f * (hxx + hyy);
                float hsd = 0.5f * (hxx - hyy);
                float hs = sqrtf(hsd*hsd + hxy*hxy + EPS_);
                lmx4[q] = hm + hs; lmn4[q] = hm - hs;
            }
            STORE4(5, lap4); STORE4(6, lmx4); STORE4(7, lmn4);
        }
        {
            float dv4[4];
            #pragma unroll
            for (int q = 0; q < 4; ++q) {
                float md  = 0.25f * (gx4[q] + gy4[q] + gdm4[q] + gda4[q]);
                float m2d = 0.25f * (gx4[q]*gx4[q] + gy4[q]*gy4[q] + gdm4[q]*gdm4[q] + gda4[q]*gda4[q]);
                dv4[q] = m2d - md * md;
            }
            STORE4(9, dv4);
        }

        float hf4[4];
        {
            float gir4[4];
            #pragma unroll
            for (int q = 0; q < 4; ++q) {
                float sumx = t[1][q+2] + t[2][q+1] + t[2][q+3] + t[3][q+2];
                float sumc = t[1][q+1] + t[1][q+3] + t[3][q+1] + t[3][q+3];
                hf4[q] = (sumc - 2.f*sumx + 4.f*t[2][q+2]) * 0.0625f;
                float gcross = 0.25f * sumx;
                gir4[q] = ((ty & 1) == (q & 1)) ? (t[2][q+2] - gcross) : 0.f;
            }
            STORE4(17, gir4);
        }
        {
            float pr = (float)(ty & 1);
            float rm4[4] = {pr, 0.f, pr, 0.f};
            float bm4[4] = {0.f, 1.f - pr, 0.f, 1.f - pr};
            float gm4[4] = {1.f - pr, pr, 1.f - pr, pr};
            STORE4(11, rm4); STORE4(12, gm4); STORE4(13, bm4);
        }
        {
            float dgc4[4];
            #pragma unroll
            for (int q = 0; q < 4; ++q) {
                float gh = 0.5f*(t[2][q+1] + t[2][q+2] + t[2][q+3]) - 0.25f*(t[2][q] + t[2][q+4]);
                float gv = 0.5f*(t[1][q+2] + t[2][q+2] + t[3][q+2]) - 0.25f*(t[0][q+2] + t[4][q+2]);
                dgc4[q] = fabsf(gh - gv);
            }
            STORE4(18, dgc4);
        }

        // gabors (hardcoded weights; g135 = column mirror)
        {
            float g45[4] = {0.f,0.f,0.f,0.f}, g135[4] = {0.f,0.f,0.f,0.f};
            #pragma unroll
            for (int dy = 0; dy < 5; ++dy) {
                #pragma unroll
                for (int dx = 0; dx < 5; ++dx) {
                    const float w = GW[dy * 5 + dx];
                    #pragma unroll
                    for (int q = 0; q < 4; ++q) {
                        g45[q]  = fmaf(w, t[dy][q + dx],     g45[q]);
                        g135[q] = fmaf(w, t[dy][q + 4 - dx], g135[q]);
                    }
                }
            }
            float oe4[4];
            #pragma unroll
            for (int q = 0; q < 4; ++q) oe4[q] = sqrtf(g45[q]*g45[q] + g135[q]*g135[q] + EPS_);
            STORE4(10, oe4);
        }

        // separable 5x5 bank via register column-profiles
        {
            float Vo[8], Va[8], Vs_[8], Vc_[8], Vd_[8];
            #pragma unroll
            for (int c = 0; c < 8; ++c) {
                float v0=t[0][c], v1=t[1][c], v2=t[2][c], v3=t[3][c], v4=t[4][c];
                Vo[c] = v0 + v1 + v2 + v3 + v4;
                Va[c] = v0 - v1 + v2 - v3 + v4;
                Vs_[c] = 0.95105651629515f*(v1 - v4) + 0.58778525229247f*(v2 - v3);
                Vc_[c] = v0 + 0.30901699437495f*(v1 + v4) - 0.80901699437495f*(v2 + v3);
                Vd_[c] = 0.80901699437495f*(v0 + v4) - 0.30901699437495f*(v1 + v3) - v2;
            }
            float cb4[4], sh4[4], sv4[4], sx4[4], sy4[4], ph4[4], hb4[4];
            #pragma unroll
            for (int q = 0; q < 4; ++q) {
                float box = Vo[q] + Vo[q+1] + Vo[q+2] + Vo[q+3] + Vo[q+4];
                float shr = Vo[q] - Vo[q+1] + Vo[q+2] - Vo[q+3] + Vo[q+4];
                float sxr = 0.95105651629515f*(Vo[q+1] - Vo[q+4]) + 0.58778525229247f*(Vo[q+2] - Vo[q+3]);
                float pxr = Vo[q] + 0.30901699437495f*(Vo[q+1] + Vo[q+4]) - 0.80901699437495f*(Vo[q+2] + Vo[q+3]);
                float cbr = Va[q] - Va[q+1] + Va[q+2] - Va[q+3] + Va[q+4];
                float svr = Va[q] + Va[q+1] + Va[q+2] + Va[q+3] + Va[q+4];
                float syr = Vs_[q] + Vs_[q+1] + Vs_[q+2] + Vs_[q+3] + Vs_[q+4];
                float pyr = Vc_[q] + Vc_[q+1] + Vc_[q+2] + Vc_[q+3] + Vc_[q+4];
                float dctr = 0.80901699437495f*(Vd_[q] + Vd_[q+4]) - 0.30901699437495f*(Vd_[q+1] + Vd_[q+3]) - Vd_[q+2];

                cb4[q] = fabsf((cbr - 0.04f * box) * 0.04006410256410f);
                sh4[q] = (shr - 0.2f * box) * 0.04166666666667f;
                sv4[q] = (svr - 0.2f * box) * 0.04166666666667f;
                sx4[q] = sxr * 0.06498394f;
                sy4[q] = syr * 0.06498394f;
                float px_n = pxr * 0.06180339887f;
                float py_n = pyr * 0.06180339887f;
                ph4[q] = sqrtf(px_n*px_n + py_n*py_n + EPS_);
                float dct_n = dctr * 0.09549150281f;
                hb4[q] = sqrtf(dct_n*dct_n + hf4[q]*hf4[q] + EPS_);
            }
            STORE4(21, cb4); STORE4(22, sh4); STORE4(23, sv4);
            STORE4(24, sh4); STORE4(25, sv4); STORE4(26, ph4);
            STORE4(27, sx4); STORE4(28, sy4); STORE4(29, hb4);
        }

        // gpd
        {
            float4 gp = *(const float4*)(sGPD + ty * 32 + tx4);
            float gp4[4] = {gp.x, gp.y, gp.z, gp.w};
            STORE4(14, gp4);
        }
    }
}

extern "C" void kernel_launch(void* const* d_in, const int* in_sizes, int n_in,
                              void* d_out, int out_size, void* d_ws, size_t ws_size,
                              hipStream_t stream) {
    const float* bayer = (const float*)d_in[0];
    float* out = (float*)d_out;
    (void)in_sizes; (void)n_in; (void)out_size; (void)d_ws; (void)ws_size;

    dim3 grid(W_ / TILE, H_ / TILE, 4);
    bayer_feat_kernel<<<grid, dim3(256), 0, stream>>>(bayer, out);
}